// Round 25
// baseline (151.385 us; speedup 1.0000x reference)
//
#include <hip/hip_runtime.h>
#include <hip/hip_bf16.h>

typedef __bf16 bf16x8 __attribute__((ext_vector_type(8)));
typedef __bf16 bf16x4 __attribute__((ext_vector_type(4)));
typedef float  f32x4  __attribute__((ext_vector_type(4)));

__device__ __forceinline__ bf16x8 cat8(bf16x4 a, bf16x4 b) {
  return __builtin_shufflevector(a, b, 0, 1, 2, 3, 4, 5, 6, 7);
}

#define MFMA16(A, B, C) __builtin_amdgcn_mfma_f32_16x16x32_bf16((A), (B), (C), 0, 0, 0)

// problem sizes (fixed)
static constexpr int TB = 4;        // batch
static constexpr int TT = 2048;     // seq len
static constexpr int TC = 1024;     // embd
static constexpr int TH = 16;       // heads
static constexpr int TD = 64;       // head dim
static constexpr int TM = TB * TT;  // 8192 token rows

// async global->LDS, 16B per lane; LDS dest must be wave-uniform base (lane*16 implied)
__device__ __forceinline__ void gload16(const __bf16* g, __bf16* l) {
  __builtin_amdgcn_global_load_lds(
      (const __attribute__((address_space(1))) unsigned int*)g,
      (__attribute__((address_space(3))) unsigned int*)l, 16, 0, 0);
}

// ---------------------------------------------------------------------------
// fused prep: x->bf16 convert (blocks 0..2047, bf16x8 16B stores) +
// W_attn transpose (2048..2815) + W_proj transpose (2816..3071).
// Branch is block-uniform.
__device__ __forceinline__ void transpose_tile(const float* __restrict__ w,
                                               __bf16* __restrict__ wt,
                                               int K, int N, int bx, int by,
                                               __bf16 (*tile)[72], int tid) {
  const int k0 = by * 64, n0 = bx * 64;
#pragma unroll
  for (int it = 0; it < 4; ++it) {
    int c = tid + it * 256;
    int row = c >> 4, cc = (c & 15) * 4;
    float4 v = *(const float4*)(w + (size_t)(k0 + row) * N + n0 + cc);
    tile[row][cc + 0] = (__bf16)v.x;
    tile[row][cc + 1] = (__bf16)v.y;
    tile[row][cc + 2] = (__bf16)v.z;
    tile[row][cc + 3] = (__bf16)v.w;
  }
  __syncthreads();
#pragma unroll
  for (int it = 0; it < 2; ++it) {
    int c = tid + it * 256;
    int n = c >> 3, kk = (c & 7) * 8;
    bf16x8 v;
#pragma unroll
    for (int j = 0; j < 8; ++j) v[j] = tile[kk + j][n];
    *(bf16x8*)(wt + (size_t)(n0 + n) * K + k0 + kk) = v;
  }
}

__global__ __launch_bounds__(256) void k_prep(const float* __restrict__ x,
                                              __bf16* __restrict__ xb,
                                              const float* __restrict__ Wa,
                                              __bf16* __restrict__ wat,
                                              const float* __restrict__ Wp,
                                              __bf16* __restrict__ wpt) {
  __shared__ __align__(16) __bf16 tile[64][72];
  const int bid = blockIdx.x, tid = threadIdx.x;
  if (bid < 2048) {
    const int n8 = (TM * TC) / 8;
    const int stride = 2048 * 256;
    for (int i = bid * 256 + tid; i < n8; i += stride) {
      float4 v0 = *(const float4*)(x + (size_t)i * 8);
      float4 v1 = *(const float4*)(x + (size_t)i * 8 + 4);
      bf16x8 o;
      o[0] = (__bf16)v0.x; o[1] = (__bf16)v0.y; o[2] = (__bf16)v0.z; o[3] = (__bf16)v0.w;
      o[4] = (__bf16)v1.x; o[5] = (__bf16)v1.y; o[6] = (__bf16)v1.z; o[7] = (__bf16)v1.w;
      *(bf16x8*)(xb + (size_t)i * 8) = o;
    }
  } else if (bid < 2816) {
    const int b2 = bid - 2048;  // 768 = 48 x 16
    transpose_tile(Wa, wat, 1024, 3072, b2 % 48, b2 / 48, tile, tid);
  } else {
    const int b2 = bid - 2816;  // 256 = 16 x 16
    transpose_tile(Wp, wpt, 1024, 1024, b2 % 16, b2 / 16, tile, tid);
  }
}

// ---------------------------------------------------------------------------
// C[M][N] = A[M][1024] @ Bt[N][1024]^T, bf16 in / f32 acc.
// r15 GEMM core (validated ~60 us / 858 TF): BK=64 tiles [128][64] (32KB)
// staged via gload16 with pre-swizzled source chunk (c ^ (r&7)) + same XOR
// on fragment reads; 16 K-steps x 32 MFMA.
// EPI==0: store f32 to outf[M][N].
// EPI==1: scatter q (scaled 0.125*log2e) / k to [B][H][T][D]; V transposed
//         to Vt [B][H][D][T'] where T' is KEY-PERMUTED within each 64-block
//         (pos = keep bit5, bits[3:2]->[4:3], bit4->bit2) so the attention
//         kernel's natural b128 LDS read delivers the in-register-P slot
//         order (r23-validated: bank conflicts -> 0).
template <int EPI>
__global__ __launch_bounds__(256, 3) void k_gemm(const __bf16* __restrict__ A,
                                                 const __bf16* __restrict__ Bt,
                                                 int N, float* __restrict__ outf,
                                                 __bf16* __restrict__ Qo,
                                                 __bf16* __restrict__ Ko,
                                                 __bf16* __restrict__ Vto) {
  __shared__ __align__(16) __bf16 As[128 * 64];
  __shared__ __align__(16) __bf16 Bs[128 * 64];
  // XCD-aware swizzle (nwg % 8 == 0 for both launches)
  const int gx = gridDim.x;
  const int nwg = gx * gridDim.y;
  int id = blockIdx.y * gx + blockIdx.x;
  id = (id & 7) * (nwg >> 3) + (id >> 3);
  const int bm = id / gx, bn = id % gx;
  const int tid = threadIdx.x, lane = tid & 63, wid = tid >> 6;
  const int wr = wid >> 1, wc = wid & 1;
  const int lr = lane & 15, lg = lane >> 4;

  f32x4 acc[4][4];
  const f32x4 zero = {0.f, 0.f, 0.f, 0.f};
#pragma unroll
  for (int mi = 0; mi < 4; ++mi)
#pragma unroll
    for (int ni = 0; ni < 4; ++ni) acc[mi][ni] = zero;

  const __bf16* Ab = A + (size_t)bm * 128 * 1024;
  const __bf16* Bb = Bt + (size_t)bn * 128 * 1024;

  // staging: 1024 16B-chunks per matrix (128 rows x 8 chunks); thread covers
  // slots it*256 + tid, it=0..3. LDS chunk (r,c) holds global chunk (r, c^(r&7)).
  const int rr = wid * 8 + (lane >> 3);     // row within each 32-row it-slab
  const int sc = (lane & 7) ^ (lane >> 3);  // pre-swizzled source chunk

  // fragment read offsets: elem = row*64 + ((L ^ (row&7))*8), L = kk*4+lg
  int offA[4][2], offB[4][2];
#pragma unroll
  for (int i = 0; i < 4; ++i)
#pragma unroll
    for (int kk = 0; kk < 2; ++kk) {
      const int xo = ((((kk << 2) + lg) ^ (lr & 7)) << 3);
      offA[i][kk] = (wr * 64 + i * 16 + lr) * 64 + xo;
      offB[i][kk] = (wc * 64 + i * 16 + lr) * 64 + xo;
    }

  for (int k0 = 0; k0 < 1024; k0 += 64) {
#pragma unroll
    for (int it = 0; it < 4; ++it) {
      const int r = it * 32 + rr;
      gload16(Ab + (size_t)r * 1024 + k0 + sc * 8, As + it * 2048 + wid * 512);
      gload16(Bb + (size_t)r * 1024 + k0 + sc * 8, Bs + it * 2048 + wid * 512);
    }
    __syncthreads();  // vmcnt(0) drain inserted by compiler

    bf16x8 af[4][2], bfr[4][2];
#pragma unroll
    for (int mi = 0; mi < 4; ++mi)
#pragma unroll
      for (int kk = 0; kk < 2; ++kk) {
        af[mi][kk]  = *(const bf16x8*)&As[offA[mi][kk]];
        bfr[mi][kk] = *(const bf16x8*)&Bs[offB[mi][kk]];
      }
#pragma unroll
    for (int mi = 0; mi < 4; ++mi)
#pragma unroll
      for (int ni = 0; ni < 4; ++ni) {
        acc[mi][ni] = MFMA16(af[mi][0], bfr[ni][0], acc[mi][ni]);
        acc[mi][ni] = MFMA16(af[mi][1], bfr[ni][1], acc[mi][ni]);
      }
    __syncthreads();  // protect LDS from next iteration's staging
  }

  // epilogue. C layout: row = (lane>>4)*4 + j, col = lane&15 (m89-verified)
  const int rb = bm * 128 + wr * 64 + lg * 4;
  const int cb = bn * 128 + wc * 64 + lr;
  if constexpr (EPI == 0) {
#pragma unroll
    for (int mi = 0; mi < 4; ++mi)
#pragma unroll
      for (int ni = 0; ni < 4; ++ni)
#pragma unroll
        for (int j = 0; j < 4; ++j)
          outf[(size_t)(rb + mi * 16 + j) * N + cb + ni * 16] = acc[mi][ni][j];
  } else {
    const int which = (bn * 128) >> 10;  // block-uniform: 0=q, 1=k, 2=v
    if (which == 2) {
      // V transposed + key-permuted: 4 consecutive t at fixed d (t0 4-aligned)
      // map to 4 consecutive permuted positions (bit shuffle below).
#pragma unroll
      for (int mi = 0; mi < 4; ++mi) {
        const int r0 = rb + mi * 16;
        const int b = r0 >> 11, t0 = r0 & 2047;
        // pos = (t&~63) | bit5 | bits[3:2]<<1 | bit4>>2
        const int p0 = (t0 & ~63) | (t0 & 32) | ((t0 & 12) << 1) | ((t0 & 16) >> 2);
#pragma unroll
        for (int ni = 0; ni < 4; ++ni) {
          const int c = cb + ni * 16;
          const int h = (c & 1023) >> 6, d = c & 63;
          bf16x4 pk;
#pragma unroll
          for (int j = 0; j < 4; ++j) pk[j] = (__bf16)acc[mi][ni][j];
          *(bf16x4*)(Vto + (((size_t)(b * TH + h) * TD + d) * TT) + p0) = pk;
        }
      }
    } else {
#pragma unroll
      for (int mi = 0; mi < 4; ++mi) {
#pragma unroll
        for (int ni = 0; ni < 4; ++ni) {
#pragma unroll
          for (int j = 0; j < 4; ++j) {
            float v = acc[mi][ni][j];
            int r = rb + mi * 16 + j;
            int c = cb + ni * 16;
            int within = c & 1023;
            int h = within >> 6, d = within & 63;
            int b = r >> 11, t = r & 2047;
            size_t idx = (((size_t)(b * TH + h)) * TT + t) * TD + d;
            if (which == 0)
              Qo[idx] = (__bf16)(v * 0.18033688f);  // 0.125 * log2(e) folded
            else
              Ko[idx] = (__bf16)v;
          }
        }
      }
    }
  }
}

// ---------------------------------------------------------------------------
// causal flash attention v15 = r24 (in-register P, key-permuted Vt, matrix-
// pipe denominator, zero bank conflicts) + DIAGONAL SUB-TILE SKIP: on the
// diag key-tile (t==c, the only tile with diag true), wave w's q-rows are
// c*64+w*16..+15, so key-fragments kf>w are entirely above the diagonal —
// their S-MFMAs/exp2s produce exact zeros. Skip them (wave-uniform) and
// write zero pk[kf] directly (bit-identical: exp2(-16384)=0 before).
// Q [bh][t][d] (pre-scaled), K [bh][t][d], Vt [bh][d][t']; Y bf16 [b*T+t][C]
__global__ __launch_bounds__(256, 3) void k_attn(const __bf16* __restrict__ Qg,
                                                 const __bf16* __restrict__ Kg,
                                                 const __bf16* __restrict__ Vt,
                                                 __bf16* __restrict__ Y) {
  __shared__ __align__(16) __bf16 Ksh[2][64 * 64];  // [key][d], XOR-swizzled
  __shared__ __align__(16) __bf16 Vsh[2][64 * 64];  // [d][key'], XOR-swizzled
  // flat id: x (pair, 0..15) fastest, y = bh. XCD k gets bh in [8k, 8k+8).
  const int flat = blockIdx.x + (blockIdx.y << 4);
  const int W = (flat & 7) * 128 + (flat >> 3);
  const int bh = W >> 4, p = W & 15;
  const int tid = threadIdx.x, lane = tid & 63, w = tid >> 6;
  const int lr = lane & 15, lg = lane >> 4, lg8 = lg << 3, lg4 = lg << 2;

  const __bf16* Qb = Qg + ((size_t)bh * TT) * TD;
  const __bf16* Kb = Kg + ((size_t)bh * TT) * TD;
  const __bf16* Vb = Vt + ((size_t)bh * TD) * TT;
  const int b = bh >> 4, hh = bh & 15;
  __bf16* Yb = Y + ((size_t)b * TT) * TC + hh * TD;

  const int c0 = p, c1 = 31 - p;       // two 64-row q chunks
  const int nkt0 = c0 + 1;
  const int nt = nkt0 + c1 + 1;        // = 33 for every block

  const f32x4 zero = {0.f, 0.f, 0.f, 0.f};
  const bf16x4 zero4 = {(__bf16)0.f, (__bf16)0.f, (__bf16)0.f, (__bf16)0.f};
  bf16x8 ones8;
#pragma unroll
  for (int j = 0; j < 8; ++j) ones8[j] = (__bf16)1.0f;

  // staging: 512 16B-chunks per tensor; thread covers slots tid, tid+256.
  // LDS slot (row, c16) holds global chunk (row, c16 ^ (row&7)) -> read with
  // the same XOR kills the stride-128B 16-way bank conflict (G4/m173).
  auto STAGE = [&](int bb, int kb) {
#pragma unroll
    for (int it = 0; it < 2; ++it) {
      int slot = tid + (it << 8);
      int r = slot >> 3;
      int sc = (slot & 7) ^ (r & 7);
      gload16(Kb + (size_t)(kb + r) * TD + sc * 8, &Ksh[bb][(it << 11) + (w << 9)]);
      gload16(Vb + (size_t)r * TT + kb + sc * 8, &Vsh[bb][(it << 11) + (w << 9)]);
    }
  };

  // loop-invariant LDS read offsets (b128 for BOTH K [row=key] and V [row=d];
  // V's slot order comes from the global key permutation, not the read):
  // off[i][h] = (i*16+lr)*64 + (((h<<2)+lg)^(lr&7))*8
  int off[4][2];
#pragma unroll
  for (int i = 0; i < 4; ++i)
#pragma unroll
    for (int h = 0; h < 2; ++h)
      off[i][h] = (i * 16 + lr) * 64 + ((((h << 2) + lg) ^ (lr & 7)) << 3);

  // per-chunk state
  int qw = c0 * 64 + w * 16;
  bf16x8 qf[2];
#pragma unroll
  for (int h = 0; h < 2; ++h)
    qf[h] = *(const bf16x8*)(Qb + (size_t)(qw + lr) * TD + h * 32 + lg8);
  f32x4 o[4];
  f32x4 ol = zero;  // denominator, same C-layout rows as o
#pragma unroll
  for (int df = 0; df < 4; ++df) o[df] = zero;

  auto epilogue = [&]() {
#pragma unroll
    for (int j = 0; j < 4; ++j) {
      const float invr = 1.0f / ol[j];       // row qw+lg4+j, in-lane
      const int row = qw + lg4 + j;
#pragma unroll
      for (int df = 0; df < 4; ++df)
        Yb[(size_t)row * TC + df * 16 + lr] = (__bf16)(o[df][j] * invr);
    }
  };

  int cur = 0;
  STAGE(0, 0);
  __syncthreads();  // compiler drains vmcnt before s_barrier

  for (int t = 0; t < nt; ++t) {
    // issue next tile's staging first (flies under this tile's compute)
    if (t + 1 < nt) {
      int t2 = t + 1;
      int kb2 = (t2 < nkt0 ? t2 : t2 - nkt0) << 6;
      STAGE(cur ^ 1, kb2);
    }
    // chunk transition: write chunk0 output, reset, load chunk1's Q
    if (t == nkt0) {
      epilogue();
      qw = c1 * 64 + w * 16;
#pragma unroll
      for (int h = 0; h < 2; ++h)
        qf[h] = *(const bf16x8*)(Qb + (size_t)(qw + lr) * TD + h * 32 + lg8);
      ol = zero;
#pragma unroll
      for (int df = 0; df < 4; ++df) o[df] = zero;
    }

    const int kb = (t < nkt0 ? t : t - nkt0) << 6;
    const __bf16* Kt = Ksh[cur];
    const __bf16* Vst = Vsh[cur];
    const bool diag = (kb + 63 > qw);  // true only on the diagonal tile

    // K as A-frag from LDS: row(key)=kf*16+lr, d-chunk = (4h+lg)^(lr&7)
    bf16x8 kA[4][2];
#pragma unroll
    for (int kf = 0; kf < 4; ++kf)
#pragma unroll
      for (int h = 0; h < 2; ++h)
        kA[kf][h] = *(const bf16x8*)&Kt[off[kf][h]];

    // S^T = K Q^T: C[row=key=kf*16+lg*4+j][col=q=lr]; already log2-scaled.
    // Diag tile: kf>w sub-tiles are fully masked -> skip their MFMAs.
    f32x4 s4[4];
    __builtin_amdgcn_s_setprio(1);
#pragma unroll
    for (int kf = 0; kf < 4; ++kf) {
      if (diag && kf > w) continue;  // wave-uniform skip
      f32x4 z = zero;
      z = MFMA16(kA[kf][0], qf[0], z);
      z = MFMA16(kA[kf][1], qf[1], z);
      s4[kf] = z;
    }
    __builtin_amdgcn_s_setprio(0);

    // exp phase: p = exp2(s) directly; pack P IN-REGISTER (no LDS roundtrip):
    // pa[h] slots 0-3 = s4[2h] (keys 32h+lg4+j), 4-7 = s4[2h+1] (+16).
    // Diag-masked kf>w sub-tiles get literal zeros (identical to exp2(-inf)).
    bf16x8 pa0, pa1;
    {
      const int q = qw + lr;
      bf16x4 pk[4];
#pragma unroll
      for (int kf = 0; kf < 4; ++kf) {
        if (diag && kf > w) { pk[kf] = zero4; continue; }  // wave-uniform
#pragma unroll
        for (int j = 0; j < 4; ++j) {
          float arg = s4[kf][j];
          if (diag) {
            int key = kb + kf * 16 + lg4 + j;
            if (key > q) arg = -16384.0f;
          }
          s4[kf][j] = __builtin_amdgcn_exp2f(arg);
        }
#pragma unroll
        for (int j = 0; j < 4; ++j) pk[kf][j] = (__bf16)s4[kf][j];
      }
      pa0 = cat8(pk[0], pk[1]);
      pa1 = cat8(pk[2], pk[3]);
    }

    // V as B-frag: natural b128 reads (conflict-free, same pattern as K);
    // the global key permutation already put keys in the pa slot order.
    bf16x8 vB[4][2];
#pragma unroll
    for (int df = 0; df < 4; ++df)
#pragma unroll
      for (int h = 0; h < 2; ++h)
        vB[df][h] = *(const bf16x8*)&Vst[off[df][h]];

    // PV: o += P @ V; ol += P @ ones (denominator on the matrix pipe —
    // output row index lg*4+j matches o's rows, no epilogue shuffles)
    __builtin_amdgcn_s_setprio(1);
#pragma unroll
    for (int df = 0; df < 4; ++df) {
      o[df] = MFMA16(pa0, vB[df][0], o[df]);
      o[df] = MFMA16(pa1, vB[df][1], o[df]);
    }
    ol = MFMA16(pa0, ones8, ol);
    ol = MFMA16(pa1, ones8, ol);
    __builtin_amdgcn_s_setprio(0);

    __syncthreads();  // staged buf ready for all; buf[cur] free to overwrite
    cur ^= 1;
  }

  epilogue();  // chunk1
}

// ---------------------------------------------------------------------------
extern "C" void kernel_launch(void* const* d_in, const int* in_sizes, int n_in,
                              void* d_out, int out_size, void* d_ws, size_t ws_size,
                              hipStream_t stream) {
  const float* x  = (const float*)d_in[0];
  const float* Wa = (const float*)d_in[1];
  const float* Wp = (const float*)d_in[2];
  float* out = (float*)d_out;

  char* ws = (char*)d_ws;
  size_t off = 0;
  auto alloc = [&](size_t bytes) { char* p = ws + off; off += bytes; return p; };
  __bf16* xb   = (__bf16*)alloc((size_t)TM * TC * 2);        // 16.8 MB (reused as Y)
  __bf16* wat  = (__bf16*)alloc((size_t)3 * TC * TC * 2);    //  6.3 MB
  __bf16* wpt  = (__bf16*)alloc((size_t)TC * TC * 2);        //  2.1 MB
  __bf16* Qb   = (__bf16*)alloc((size_t)TM * TC * 2);        // 16.8 MB
  __bf16* Kb   = (__bf16*)alloc((size_t)TM * TC * 2);        // 16.8 MB
  __bf16* Vtb  = (__bf16*)alloc((size_t)TM * TC * 2);        // 16.8 MB
  __bf16* Yb   = xb;  // x_bf16 dead after GEMM1; alias as attention output

  // 1. fused prep: x->bf16 + both W transposes (independent; one launch)
  k_prep<<<3072, 256, 0, stream>>>(x, xb, Wa, wat, Wp, wpt);
  // 2. qkv = x @ W_attn; q,k -> [B][H][T][D], v -> Vt [B][H][D][T'] (fused)
  k_gemm<1><<<dim3(24, 64), 256, 0, stream>>>(xb, wat, 3072, nullptr, Qb, Kb, Vtb);
  // 3. causal flash attention -> Y bf16 [B*T][C]
  k_attn<<<dim3(16, 64), 256, 0, stream>>>(Qb, Kb, Vtb, Yb);
  // 4. out = Y @ W_proj (f32 out)
  k_gemm<0><<<dim3(8, 64), 256, 0, stream>>>(Yb, wpt, 1024, out, nullptr, nullptr, nullptr);
}

// Round 26
// 150.735 us; speedup vs baseline: 1.0043x; 1.0043x over previous
//
#include <hip/hip_runtime.h>
#include <hip/hip_bf16.h>

typedef __bf16 bf16x8 __attribute__((ext_vector_type(8)));
typedef __bf16 bf16x4 __attribute__((ext_vector_type(4)));
typedef float  f32x4  __attribute__((ext_vector_type(4)));

__device__ __forceinline__ bf16x8 cat8(bf16x4 a, bf16x4 b) {
  return __builtin_shufflevector(a, b, 0, 1, 2, 3, 4, 5, 6, 7);
}

#define MFMA16(A, B, C) __builtin_amdgcn_mfma_f32_16x16x32_bf16((A), (B), (C), 0, 0, 0)

// problem sizes (fixed)
static constexpr int TB = 4;        // batch
static constexpr int TT = 2048;     // seq len
static constexpr int TC = 1024;     // embd
static constexpr int TH = 16;       // heads
static constexpr int TD = 64;       // head dim
static constexpr int TM = TB * TT;  // 8192 token rows

// async global->LDS, 16B per lane; LDS dest must be wave-uniform base (lane*16 implied)
__device__ __forceinline__ void gload16(const __bf16* g, __bf16* l) {
  __builtin_amdgcn_global_load_lds(
      (const __attribute__((address_space(1))) unsigned int*)g,
      (__attribute__((address_space(3))) unsigned int*)l, 16, 0, 0);
}

// ---------------------------------------------------------------------------
// fused prep: x->bf16 convert (blocks 0..2047, bf16x8 16B stores) +
// W_attn transpose (2048..2815) + W_proj transpose (2816..3071).
// Branch is block-uniform.
__device__ __forceinline__ void transpose_tile(const float* __restrict__ w,
                                               __bf16* __restrict__ wt,
                                               int K, int N, int bx, int by,
                                               __bf16 (*tile)[72], int tid) {
  const int k0 = by * 64, n0 = bx * 64;
#pragma unroll
  for (int it = 0; it < 4; ++it) {
    int c = tid + it * 256;
    int row = c >> 4, cc = (c & 15) * 4;
    float4 v = *(const float4*)(w + (size_t)(k0 + row) * N + n0 + cc);
    tile[row][cc + 0] = (__bf16)v.x;
    tile[row][cc + 1] = (__bf16)v.y;
    tile[row][cc + 2] = (__bf16)v.z;
    tile[row][cc + 3] = (__bf16)v.w;
  }
  __syncthreads();
#pragma unroll
  for (int it = 0; it < 2; ++it) {
    int c = tid + it * 256;
    int n = c >> 3, kk = (c & 7) * 8;
    bf16x8 v;
#pragma unroll
    for (int j = 0; j < 8; ++j) v[j] = tile[kk + j][n];
    *(bf16x8*)(wt + (size_t)(n0 + n) * K + k0 + kk) = v;
  }
}

__global__ __launch_bounds__(256) void k_prep(const float* __restrict__ x,
                                              __bf16* __restrict__ xb,
                                              const float* __restrict__ Wa,
                                              __bf16* __restrict__ wat,
                                              const float* __restrict__ Wp,
                                              __bf16* __restrict__ wpt) {
  __shared__ __align__(16) __bf16 tile[64][72];
  const int bid = blockIdx.x, tid = threadIdx.x;
  if (bid < 2048) {
    const int n8 = (TM * TC) / 8;
    const int stride = 2048 * 256;
    for (int i = bid * 256 + tid; i < n8; i += stride) {
      float4 v0 = *(const float4*)(x + (size_t)i * 8);
      float4 v1 = *(const float4*)(x + (size_t)i * 8 + 4);
      bf16x8 o;
      o[0] = (__bf16)v0.x; o[1] = (__bf16)v0.y; o[2] = (__bf16)v0.z; o[3] = (__bf16)v0.w;
      o[4] = (__bf16)v1.x; o[5] = (__bf16)v1.y; o[6] = (__bf16)v1.z; o[7] = (__bf16)v1.w;
      *(bf16x8*)(xb + (size_t)i * 8) = o;
    }
  } else if (bid < 2816) {
    const int b2 = bid - 2048;  // 768 = 48 x 16
    transpose_tile(Wa, wat, 1024, 3072, b2 % 48, b2 / 48, tile, tid);
  } else {
    const int b2 = bid - 2816;  // 256 = 16 x 16
    transpose_tile(Wp, wpt, 1024, 1024, b2 % 16, b2 / 16, tile, tid);
  }
}

// ---------------------------------------------------------------------------
// C[M][N] = A[M][1024] @ Bt[N][1024]^T, bf16 in / f32 acc.
// r15 GEMM core (validated ~60 us / 858 TF): BK=64 tiles [128][64] (32KB)
// staged via gload16 with pre-swizzled source chunk (c ^ (r&7)) + same XOR
// on fragment reads; 16 K-steps x 32 MFMA.
// EPI==0: store f32 to outf[M][N].
// EPI==1: scatter q (scaled 0.125*log2e) / k to [B][H][T][D]; V transposed
//         to Vt [B][H][D][T'] where T' is KEY-PERMUTED within each 64-block
//         (pos = keep bit5, bits[3:2]->[4:3], bit4->bit2) so the attention
//         kernel's natural b128 LDS read delivers the in-register-P slot
//         order (r23-validated: bank conflicts -> 0).
template <int EPI>
__global__ __launch_bounds__(256, 3) void k_gemm(const __bf16* __restrict__ A,
                                                 const __bf16* __restrict__ Bt,
                                                 int N, float* __restrict__ outf,
                                                 __bf16* __restrict__ Qo,
                                                 __bf16* __restrict__ Ko,
                                                 __bf16* __restrict__ Vto) {
  __shared__ __align__(16) __bf16 As[128 * 64];
  __shared__ __align__(16) __bf16 Bs[128 * 64];
  // XCD-aware swizzle (nwg % 8 == 0 for both launches)
  const int gx = gridDim.x;
  const int nwg = gx * gridDim.y;
  int id = blockIdx.y * gx + blockIdx.x;
  id = (id & 7) * (nwg >> 3) + (id >> 3);
  const int bm = id / gx, bn = id % gx;
  const int tid = threadIdx.x, lane = tid & 63, wid = tid >> 6;
  const int wr = wid >> 1, wc = wid & 1;
  const int lr = lane & 15, lg = lane >> 4;

  f32x4 acc[4][4];
  const f32x4 zero = {0.f, 0.f, 0.f, 0.f};
#pragma unroll
  for (int mi = 0; mi < 4; ++mi)
#pragma unroll
    for (int ni = 0; ni < 4; ++ni) acc[mi][ni] = zero;

  const __bf16* Ab = A + (size_t)bm * 128 * 1024;
  const __bf16* Bb = Bt + (size_t)bn * 128 * 1024;

  // staging: 1024 16B-chunks per matrix (128 rows x 8 chunks); thread covers
  // slots it*256 + tid, it=0..3. LDS chunk (r,c) holds global chunk (r, c^(r&7)).
  const int rr = wid * 8 + (lane >> 3);     // row within each 32-row it-slab
  const int sc = (lane & 7) ^ (lane >> 3);  // pre-swizzled source chunk

  // fragment read offsets: elem = row*64 + ((L ^ (row&7))*8), L = kk*4+lg
  int offA[4][2], offB[4][2];
#pragma unroll
  for (int i = 0; i < 4; ++i)
#pragma unroll
    for (int kk = 0; kk < 2; ++kk) {
      const int xo = ((((kk << 2) + lg) ^ (lr & 7)) << 3);
      offA[i][kk] = (wr * 64 + i * 16 + lr) * 64 + xo;
      offB[i][kk] = (wc * 64 + i * 16 + lr) * 64 + xo;
    }

  for (int k0 = 0; k0 < 1024; k0 += 64) {
#pragma unroll
    for (int it = 0; it < 4; ++it) {
      const int r = it * 32 + rr;
      gload16(Ab + (size_t)r * 1024 + k0 + sc * 8, As + it * 2048 + wid * 512);
      gload16(Bb + (size_t)r * 1024 + k0 + sc * 8, Bs + it * 2048 + wid * 512);
    }
    __syncthreads();  // vmcnt(0) drain inserted by compiler

    bf16x8 af[4][2], bfr[4][2];
#pragma unroll
    for (int mi = 0; mi < 4; ++mi)
#pragma unroll
      for (int kk = 0; kk < 2; ++kk) {
        af[mi][kk]  = *(const bf16x8*)&As[offA[mi][kk]];
        bfr[mi][kk] = *(const bf16x8*)&Bs[offB[mi][kk]];
      }
#pragma unroll
    for (int mi = 0; mi < 4; ++mi)
#pragma unroll
      for (int ni = 0; ni < 4; ++ni) {
        acc[mi][ni] = MFMA16(af[mi][0], bfr[ni][0], acc[mi][ni]);
        acc[mi][ni] = MFMA16(af[mi][1], bfr[ni][1], acc[mi][ni]);
      }
    __syncthreads();  // protect LDS from next iteration's staging
  }

  // epilogue. C layout: row = (lane>>4)*4 + j, col = lane&15 (m89-verified)
  const int rb = bm * 128 + wr * 64 + lg * 4;
  const int cb = bn * 128 + wc * 64 + lr;
  if constexpr (EPI == 0) {
#pragma unroll
    for (int mi = 0; mi < 4; ++mi)
#pragma unroll
      for (int ni = 0; ni < 4; ++ni)
#pragma unroll
        for (int j = 0; j < 4; ++j)
          outf[(size_t)(rb + mi * 16 + j) * N + cb + ni * 16] = acc[mi][ni][j];
  } else {
    const int which = (bn * 128) >> 10;  // block-uniform: 0=q, 1=k, 2=v
    if (which == 2) {
      // V transposed + key-permuted: 4 consecutive t at fixed d (t0 4-aligned)
      // map to 4 consecutive permuted positions (bit shuffle below).
#pragma unroll
      for (int mi = 0; mi < 4; ++mi) {
        const int r0 = rb + mi * 16;
        const int b = r0 >> 11, t0 = r0 & 2047;
        // pos = (t&~63) | bit5 | bits[3:2]<<1 | bit4>>2
        const int p0 = (t0 & ~63) | (t0 & 32) | ((t0 & 12) << 1) | ((t0 & 16) >> 2);
#pragma unroll
        for (int ni = 0; ni < 4; ++ni) {
          const int c = cb + ni * 16;
          const int h = (c & 1023) >> 6, d = c & 63;
          bf16x4 pk;
#pragma unroll
          for (int j = 0; j < 4; ++j) pk[j] = (__bf16)acc[mi][ni][j];
          *(bf16x4*)(Vto + (((size_t)(b * TH + h) * TD + d) * TT) + p0) = pk;
        }
      }
    } else {
#pragma unroll
      for (int mi = 0; mi < 4; ++mi) {
#pragma unroll
        for (int ni = 0; ni < 4; ++ni) {
#pragma unroll
          for (int j = 0; j < 4; ++j) {
            float v = acc[mi][ni][j];
            int r = rb + mi * 16 + j;
            int c = cb + ni * 16;
            int within = c & 1023;
            int h = within >> 6, d = within & 63;
            int b = r >> 11, t = r & 2047;
            size_t idx = (((size_t)(b * TH + h)) * TT + t) * TD + d;
            if (which == 0)
              Qo[idx] = (__bf16)(v * 0.18033688f);  // 0.125 * log2(e) folded
            else
              Ko[idx] = (__bf16)v;
          }
        }
      }
    }
  }
}

// ---------------------------------------------------------------------------
// causal flash attention — r24 version VERBATIM (best measured: attn 61.2us,
// total 151.1us; r25's diag sub-tile skip was neutral-to-negative). In-register
// P (no Plds roundtrip), key-permuted Vt (natural b128 V reads, zero bank
// conflicts), matrix-pipe softmax denominator (ol += P @ ones; epilogue is an
// in-lane multiply, no shuffles), exp2 direct (log2e folded into Q), balanced
// chunk-pair blocks (c, 31-c) x 4 waves, double-buffered XOR-swizzled K/V
// staging, XCD-grouped bh, 32768B LDS.
// Q [bh][t][d] (pre-scaled), K [bh][t][d], Vt [bh][d][t']; Y bf16 [b*T+t][C]
__global__ __launch_bounds__(256, 3) void k_attn(const __bf16* __restrict__ Qg,
                                                 const __bf16* __restrict__ Kg,
                                                 const __bf16* __restrict__ Vt,
                                                 __bf16* __restrict__ Y) {
  __shared__ __align__(16) __bf16 Ksh[2][64 * 64];  // [key][d], XOR-swizzled
  __shared__ __align__(16) __bf16 Vsh[2][64 * 64];  // [d][key'], XOR-swizzled
  // flat id: x (pair, 0..15) fastest, y = bh. XCD k gets bh in [8k, 8k+8).
  const int flat = blockIdx.x + (blockIdx.y << 4);
  const int W = (flat & 7) * 128 + (flat >> 3);
  const int bh = W >> 4, p = W & 15;
  const int tid = threadIdx.x, lane = tid & 63, w = tid >> 6;
  const int lr = lane & 15, lg = lane >> 4, lg8 = lg << 3, lg4 = lg << 2;

  const __bf16* Qb = Qg + ((size_t)bh * TT) * TD;
  const __bf16* Kb = Kg + ((size_t)bh * TT) * TD;
  const __bf16* Vb = Vt + ((size_t)bh * TD) * TT;
  const int b = bh >> 4, hh = bh & 15;
  __bf16* Yb = Y + ((size_t)b * TT) * TC + hh * TD;

  const int c0 = p, c1 = 31 - p;       // two 64-row q chunks
  const int nkt0 = c0 + 1;
  const int nt = nkt0 + c1 + 1;        // = 33 for every block

  const f32x4 zero = {0.f, 0.f, 0.f, 0.f};
  bf16x8 ones8;
#pragma unroll
  for (int j = 0; j < 8; ++j) ones8[j] = (__bf16)1.0f;

  // staging: 512 16B-chunks per tensor; thread covers slots tid, tid+256.
  // LDS slot (row, c16) holds global chunk (row, c16 ^ (row&7)) -> read with
  // the same XOR kills the stride-128B 16-way bank conflict (G4/m173).
  auto STAGE = [&](int bb, int kb) {
#pragma unroll
    for (int it = 0; it < 2; ++it) {
      int slot = tid + (it << 8);
      int r = slot >> 3;
      int sc = (slot & 7) ^ (r & 7);
      gload16(Kb + (size_t)(kb + r) * TD + sc * 8, &Ksh[bb][(it << 11) + (w << 9)]);
      gload16(Vb + (size_t)r * TT + kb + sc * 8, &Vsh[bb][(it << 11) + (w << 9)]);
    }
  };

  // loop-invariant LDS read offsets (b128 for BOTH K [row=key] and V [row=d];
  // V's slot order comes from the global key permutation, not the read):
  // off[i][h] = (i*16+lr)*64 + (((h<<2)+lg)^(lr&7))*8
  int off[4][2];
#pragma unroll
  for (int i = 0; i < 4; ++i)
#pragma unroll
    for (int h = 0; h < 2; ++h)
      off[i][h] = (i * 16 + lr) * 64 + ((((h << 2) + lg) ^ (lr & 7)) << 3);

  // per-chunk state
  int qw = c0 * 64 + w * 16;
  bf16x8 qf[2];
#pragma unroll
  for (int h = 0; h < 2; ++h)
    qf[h] = *(const bf16x8*)(Qb + (size_t)(qw + lr) * TD + h * 32 + lg8);
  f32x4 o[4];
  f32x4 ol = zero;  // denominator, same C-layout rows as o
#pragma unroll
  for (int df = 0; df < 4; ++df) o[df] = zero;

  auto epilogue = [&]() {
#pragma unroll
    for (int j = 0; j < 4; ++j) {
      const float invr = 1.0f / ol[j];       // row qw+lg4+j, in-lane
      const int row = qw + lg4 + j;
#pragma unroll
      for (int df = 0; df < 4; ++df)
        Yb[(size_t)row * TC + df * 16 + lr] = (__bf16)(o[df][j] * invr);
    }
  };

  int cur = 0;
  STAGE(0, 0);
  __syncthreads();  // compiler drains vmcnt before s_barrier

  for (int t = 0; t < nt; ++t) {
    // issue next tile's staging first (flies under this tile's compute)
    if (t + 1 < nt) {
      int t2 = t + 1;
      int kb2 = (t2 < nkt0 ? t2 : t2 - nkt0) << 6;
      STAGE(cur ^ 1, kb2);
    }
    // chunk transition: write chunk0 output, reset, load chunk1's Q
    if (t == nkt0) {
      epilogue();
      qw = c1 * 64 + w * 16;
#pragma unroll
      for (int h = 0; h < 2; ++h)
        qf[h] = *(const bf16x8*)(Qb + (size_t)(qw + lr) * TD + h * 32 + lg8);
      ol = zero;
#pragma unroll
      for (int df = 0; df < 4; ++df) o[df] = zero;
    }

    const int kb = (t < nkt0 ? t : t - nkt0) << 6;
    const __bf16* Kt = Ksh[cur];
    const __bf16* Vst = Vsh[cur];

    // K as A-frag from LDS: row(key)=kf*16+lr, d-chunk = (4h+lg)^(lr&7)
    bf16x8 kA[4][2];
#pragma unroll
    for (int kf = 0; kf < 4; ++kf)
#pragma unroll
      for (int h = 0; h < 2; ++h)
        kA[kf][h] = *(const bf16x8*)&Kt[off[kf][h]];

    // S^T = K Q^T: C[row=key=kf*16+lg*4+j][col=q=lr]; already log2-scaled
    f32x4 s4[4];
    __builtin_amdgcn_s_setprio(1);
#pragma unroll
    for (int kf = 0; kf < 4; ++kf) {
      f32x4 z = zero;
      z = MFMA16(kA[kf][0], qf[0], z);
      z = MFMA16(kA[kf][1], qf[1], z);
      s4[kf] = z;
    }
    __builtin_amdgcn_s_setprio(0);

    // exp phase: p = exp2(s) directly; pack P IN-REGISTER (no LDS roundtrip):
    // pa[h] slots 0-3 = s4[2h] (keys 32h+lg4+j), 4-7 = s4[2h+1] (+16)
    bf16x8 pa0, pa1;
    {
      const int q = qw + lr;
      const bool diag = (kb + 63 > qw);  // wave-uniform
      bf16x4 pk[4];
#pragma unroll
      for (int kf = 0; kf < 4; ++kf) {
#pragma unroll
        for (int j = 0; j < 4; ++j) {
          float arg = s4[kf][j];
          if (diag) {
            int key = kb + kf * 16 + lg4 + j;
            if (key > q) arg = -16384.0f;
          }
          s4[kf][j] = __builtin_amdgcn_exp2f(arg);
        }
#pragma unroll
        for (int j = 0; j < 4; ++j) pk[kf][j] = (__bf16)s4[kf][j];
      }
      pa0 = cat8(pk[0], pk[1]);
      pa1 = cat8(pk[2], pk[3]);
    }

    // V as B-frag: natural b128 reads (conflict-free, same pattern as K);
    // the global key permutation already put keys in the pa slot order.
    bf16x8 vB[4][2];
#pragma unroll
    for (int df = 0; df < 4; ++df)
#pragma unroll
      for (int h = 0; h < 2; ++h)
        vB[df][h] = *(const bf16x8*)&Vst[off[df][h]];

    // PV: o += P @ V; ol += P @ ones (denominator on the matrix pipe —
    // output row index lg*4+j matches o's rows, no epilogue shuffles)
    __builtin_amdgcn_s_setprio(1);
#pragma unroll
    for (int df = 0; df < 4; ++df) {
      o[df] = MFMA16(pa0, vB[df][0], o[df]);
      o[df] = MFMA16(pa1, vB[df][1], o[df]);
    }
    ol = MFMA16(pa0, ones8, ol);
    ol = MFMA16(pa1, ones8, ol);
    __builtin_amdgcn_s_setprio(0);

    __syncthreads();  // staged buf ready for all; buf[cur] free to overwrite
    cur ^= 1;
  }

  epilogue();  // chunk1
}

// ---------------------------------------------------------------------------
extern "C" void kernel_launch(void* const* d_in, const int* in_sizes, int n_in,
                              void* d_out, int out_size, void* d_ws, size_t ws_size,
                              hipStream_t stream) {
  const float* x  = (const float*)d_in[0];
  const float* Wa = (const float*)d_in[1];
  const float* Wp = (const float*)d_in[2];
  float* out = (float*)d_out;

  char* ws = (char*)d_ws;
  size_t off = 0;
  auto alloc = [&](size_t bytes) { char* p = ws + off; off += bytes; return p; };
  __bf16* xb   = (__bf16*)alloc((size_t)TM * TC * 2);        // 16.8 MB (reused as Y)
  __bf16* wat  = (__bf16*)alloc((size_t)3 * TC * TC * 2);    //  6.3 MB
  __bf16* wpt  = (__bf16*)alloc((size_t)TC * TC * 2);        //  2.1 MB
  __bf16* Qb   = (__bf16*)alloc((size_t)TM * TC * 2);        // 16.8 MB
  __bf16* Kb   = (__bf16*)alloc((size_t)TM * TC * 2);        // 16.8 MB
  __bf16* Vtb  = (__bf16*)alloc((size_t)TM * TC * 2);        // 16.8 MB
  __bf16* Yb   = xb;  // x_bf16 dead after GEMM1; alias as attention output

  // 1. fused prep: x->bf16 + both W transposes (independent; one launch)
  k_prep<<<3072, 256, 0, stream>>>(x, xb, Wa, wat, Wp, wpt);
  // 2. qkv = x @ W_attn; q,k -> [B][H][T][D], v -> Vt [B][H][D][T'] (fused)
  k_gemm<1><<<dim3(24, 64), 256, 0, stream>>>(xb, wat, 3072, nullptr, Qb, Kb, Vtb);
  // 3. causal flash attention -> Y bf16 [B*T][C]
  k_attn<<<dim3(16, 64), 256, 0, stream>>>(Qb, Kb, Vtb, Yb);
  // 4. out = Y @ W_proj (f32 out)
  k_gemm<0><<<dim3(8, 64), 256, 0, stream>>>(Yb, wpt, 1024, out, nullptr, nullptr, nullptr);
}